// Round 1
// baseline (441.481 us; speedup 1.0000x reference)
//
#include <hip/hip_runtime.h>
#include <math.h>

// Problem constants
#define BATCH 4
#define C 256
#define H 128
#define W 128
#define HW (H * W)          // 16384
#define OH 256
#define OW 256
#define NPOS (BATCH * OH * OW)   // 262144 output positions
__device__ __constant__ float OFF_FACTOR = 0.70710678118654752f; // sqrt(128/256)

// Kernel A: 1x1 conv -> offsets -> bilinear descriptors.
// One thread per input pixel (b,h,w). 65536 threads.
__global__ __launch_bounds__(256) void offsets_kernel(
    const float* __restrict__ x, const float* __restrict__ cw,
    const float* __restrict__ cb, int4* __restrict__ idxbuf,
    float4* __restrict__ wbuf) {
    __shared__ float sw[8 * 256];
    int t = threadIdx.x;
    // stage conv weights into LDS (broadcast reads later)
    #pragma unroll
    for (int i = 0; i < 8; ++i) sw[t + i * 256] = cw[t + i * 256];
    __syncthreads();

    int gid = blockIdx.x * 256 + t;      // 0..65535
    int w = gid & (W - 1);
    int h = (gid >> 7) & (H - 1);
    int b = gid >> 14;

    const float* xp = x + (size_t)b * C * HW + h * W + w;
    float acc[8];
    #pragma unroll
    for (int o = 0; o < 8; ++o) acc[o] = 0.f;

    #pragma unroll 8
    for (int c = 0; c < C; ++c) {
        float v = xp[(size_t)c * HW];
        #pragma unroll
        for (int o = 0; o < 8; ++o) acc[o] += v * sw[o * 256 + c];
    }

    float bias[8];
    #pragma unroll
    for (int o = 0; o < 8; ++o) bias[o] = cb[o];

    #pragma unroll
    for (int j = 0; j < 4; ++j) {
        int sx = j & 1, sy = j >> 1;
        float xc = OFF_FACTOR * (acc[j] + bias[j]) + (float)w + 0.5f * (float)sx;
        float yc = OFF_FACTOR * (acc[4 + j] + bias[4 + j]) + (float)h + 0.5f * (float)sy;
        float x0f = floorf(xc), y0f = floorf(yc);
        float fx = xc - x0f, fy = yc - y0f;
        int x0 = (int)x0f, y0 = (int)y0f;
        int x0i = min(max(x0, 0), W - 1);
        int x1i = min(max(x0 + 1, 0), W - 1);
        int y0i = min(max(y0, 0), H - 1);
        int y1i = min(max(y0 + 1, 0), H - 1);
        int oh = h * 2 + sy;
        int ow = w * 2 + sx;
        int p = (b * OH + oh) * OW + ow;
        idxbuf[p] = make_int4(y0i * W + x0i, y0i * W + x1i,
                              y1i * W + x0i, y1i * W + x1i);
        wbuf[p] = make_float4((1.f - fx) * (1.f - fy), fx * (1.f - fy),
                              (1.f - fx) * fy,         fx * fy);
    }
}

// Kernel B: bilinear gather over all 256 channels.
// Block = (b, oh), thread = ow. Descriptor loaded once into registers.
__global__ __launch_bounds__(256) void sample_kernel(
    const float* __restrict__ x, const int4* __restrict__ idxbuf,
    const float4* __restrict__ wbuf, float* __restrict__ out) {
    int t = threadIdx.x;               // ow
    int oh = blockIdx.x & (OH - 1);
    int b = blockIdx.x >> 8;

    int p = (b * OH + oh) * OW + t;
    int4 i4 = idxbuf[p];
    float4 w4 = wbuf[p];

    const float* xp = x + (size_t)b * C * HW;
    float* op = out + (size_t)b * C * OH * OW + (size_t)oh * OW + t;

    #pragma unroll 4
    for (int c = 0; c < C; ++c) {
        const float* pl = xp + (size_t)c * HW;
        float v = pl[i4.x] * w4.x + pl[i4.y] * w4.y +
                  pl[i4.z] * w4.z + pl[i4.w] * w4.w;
        op[(size_t)c * (OH * OW)] = v;
    }
}

extern "C" void kernel_launch(void* const* d_in, const int* in_sizes, int n_in,
                              void* d_out, int out_size, void* d_ws, size_t ws_size,
                              hipStream_t stream) {
    const float* x  = (const float*)d_in[0];
    const float* cw = (const float*)d_in[1];
    const float* cb = (const float*)d_in[2];
    float* out = (float*)d_out;

    int4*   idxbuf = (int4*)d_ws;
    float4* wbuf   = (float4*)((char*)d_ws + (size_t)NPOS * sizeof(int4));

    offsets_kernel<<<(BATCH * HW) / 256, 256, 0, stream>>>(x, cw, cb, idxbuf, wbuf);
    sample_kernel<<<BATCH * OH, 256, 0, stream>>>(x, idxbuf, wbuf, out);
}

// Round 2
// 400.531 us; speedup vs baseline: 1.1022x; 1.1022x over previous
//
#include <hip/hip_runtime.h>
#include <math.h>

// Problem constants
#define BATCH 4
#define C 256
#define H 128
#define W 128
#define HW (H * W)          // 16384
#define OH 256
#define OW 256
#define NPIX (BATCH * HW)        // 65536 input pixels
#define NPOS (BATCH * OH * OW)   // 262144 output positions
#define KSPLIT 4
#define KCH (C / KSPLIT)         // 64
__device__ __constant__ float OFF_FACTOR = 0.70710678118654752f; // sqrt(128/256)

// ---------------------------------------------------------------------------
// Kernel A1: partial 1x1 conv. Split-K x4, 4 pixels per thread (float4 loads).
// Grid: 256 blocks x 256 threads. partial layout: [k][o][NPIX] floats.
// ---------------------------------------------------------------------------
__global__ __launch_bounds__(256) void conv_partial_kernel(
    const float* __restrict__ x, const float* __restrict__ cw,
    float* __restrict__ partial) {
    __shared__ float sw[8 * KCH];
    int t = threadIdx.x;
    int k = blockIdx.x >> 6;          // ksplit chunk 0..3
    int blkpix = blockIdx.x & 63;     // pixel-tile 0..63
    int kbase = k * KCH;

    // stage this chunk's weights: sw[o*64+c] = cw[o*256 + kbase + c]
    if (t < 8 * KCH / 2 * 2) {        // 512 entries, 256 threads -> 2 each
        int i0 = t, i1 = t + 256;
        sw[i0] = cw[(i0 >> 6) * C + kbase + (i0 & 63)];
        sw[i1] = cw[(i1 >> 6) * C + kbase + (i1 & 63)];
    }
    __syncthreads();

    int p4 = blkpix * 256 + t;        // float4-group index, 0..16383
    int g = p4 * 4;                   // first pixel
    int b = g >> 14;                  // batch
    int pix = g & (HW - 1);

    const float* xp = x + (size_t)b * C * HW + (size_t)kbase * HW + pix;

    float4 acc[8];
    #pragma unroll
    for (int o = 0; o < 8; ++o) acc[o] = make_float4(0.f, 0.f, 0.f, 0.f);

    #pragma unroll 8
    for (int c = 0; c < KCH; ++c) {
        float4 v = *(const float4*)(xp + (size_t)c * HW);
        #pragma unroll
        for (int o = 0; o < 8; ++o) {
            float wv = sw[o * KCH + c];
            acc[o].x += v.x * wv; acc[o].y += v.y * wv;
            acc[o].z += v.z * wv; acc[o].w += v.w * wv;
        }
    }

    #pragma unroll
    for (int o = 0; o < 8; ++o) {
        float4* dst = (float4*)(partial + ((size_t)(k * 8 + o) * NPIX) + g);
        *dst = acc[o];
    }
}

// ---------------------------------------------------------------------------
// Kernel A2: reduce split-K partials + bias -> bilinear descriptors.
// One thread per input pixel. Grid: 256 x 256.
// ---------------------------------------------------------------------------
__global__ __launch_bounds__(256) void descriptor_kernel(
    const float* __restrict__ partial, const float* __restrict__ cb,
    int4* __restrict__ idxbuf, float4* __restrict__ wbuf) {
    int g = blockIdx.x * 256 + threadIdx.x;   // 0..65535
    int w = g & (W - 1);
    int h = (g >> 7) & (H - 1);
    int b = g >> 14;

    float s[8];
    #pragma unroll
    for (int o = 0; o < 8; ++o) {
        float acc = cb[o];
        #pragma unroll
        for (int k = 0; k < KSPLIT; ++k)
            acc += partial[((size_t)(k * 8 + o) * NPIX) + g];
        s[o] = acc;
    }

    #pragma unroll
    for (int j = 0; j < 4; ++j) {
        int sx = j & 1, sy = j >> 1;
        float xc = OFF_FACTOR * s[j]     + (float)w + 0.5f * (float)sx;
        float yc = OFF_FACTOR * s[4 + j] + (float)h + 0.5f * (float)sy;
        float x0f = floorf(xc), y0f = floorf(yc);
        float fx = xc - x0f, fy = yc - y0f;
        int x0 = (int)x0f, y0 = (int)y0f;
        int x0i = min(max(x0, 0), W - 1);
        int x1i = min(max(x0 + 1, 0), W - 1);
        int y0i = min(max(y0, 0), H - 1);
        int y1i = min(max(y0 + 1, 0), H - 1);
        int oh = h * 2 + sy;
        int ow = w * 2 + sx;
        int p = (b * OH + oh) * OW + ow;
        idxbuf[p] = make_int4(y0i * W + x0i, y0i * W + x1i,
                              y1i * W + x0i, y1i * W + x1i);
        wbuf[p] = make_float4((1.f - fx) * (1.f - fy), fx * (1.f - fy),
                              (1.f - fx) * fy,         fx * fy);
    }
}

// ---------------------------------------------------------------------------
// Kernel B: bilinear gather. Block = (b, h_in, c-chunk of 64); 256 threads=ow.
// Each thread handles output rows 2h and 2h+1; descriptors loaded once.
// XCD-contiguous swizzle: consecutive ord within an XCD share input rows.
// ---------------------------------------------------------------------------
__global__ __launch_bounds__(256) void sample_kernel(
    const float* __restrict__ x, const int4* __restrict__ idxbuf,
    const float4* __restrict__ wbuf, float* __restrict__ out) {
    int t = threadIdx.x;               // ow
    int lin = blockIdx.x;              // 0..2047
    // round-robin XCD assignment (lin % 8) -> give each XCD a contiguous band
    int ord = (lin & 7) * 256 + (lin >> 3);
    int cchunk = ord & 3;
    int h = (ord >> 2) & (H - 1);
    int b = ord >> 9;

    int oh0 = 2 * h, oh1 = 2 * h + 1;
    int p0 = (b * OH + oh0) * OW + t;
    int p1 = (b * OH + oh1) * OW + t;
    int4 ia = idxbuf[p0];  float4 wa = wbuf[p0];
    int4 ib = idxbuf[p1];  float4 wb = wbuf[p1];

    int c0 = cchunk * 64;
    const float* xp = x + (size_t)b * C * HW + (size_t)c0 * HW;
    float* op = out + (((size_t)(b * C + c0) * OH + oh0) * OW) + t;

    #pragma unroll 2
    for (int c = 0; c < 64; ++c) {
        const float* pl = xp + (size_t)c * HW;
        float v0 = pl[ia.x] * wa.x + pl[ia.y] * wa.y +
                   pl[ia.z] * wa.z + pl[ia.w] * wa.w;
        float v1 = pl[ib.x] * wb.x + pl[ib.y] * wb.y +
                   pl[ib.z] * wb.z + pl[ib.w] * wb.w;
        float* o0 = op + (size_t)c * (OH * OW);
        o0[0] = v0;
        o0[OW] = v1;
    }
}

extern "C" void kernel_launch(void* const* d_in, const int* in_sizes, int n_in,
                              void* d_out, int out_size, void* d_ws, size_t ws_size,
                              hipStream_t stream) {
    const float* x  = (const float*)d_in[0];
    const float* cw = (const float*)d_in[1];
    const float* cb = (const float*)d_in[2];
    float* out = (float*)d_out;

    float* partial = (float*)d_ws;                               // 8 MB
    int4*  idxbuf  = (int4*)((char*)d_ws + (size_t)KSPLIT * 8 * NPIX * 4);
    float4* wbuf   = (float4*)((char*)idxbuf + (size_t)NPOS * sizeof(int4));

    conv_partial_kernel<<<256, 256, 0, stream>>>(x, cw, partial);
    descriptor_kernel<<<256, 256, 0, stream>>>(partial, cb, idxbuf, wbuf);
    sample_kernel<<<BATCH * H * KSPLIT, 256, 0, stream>>>(x, idxbuf, wbuf, out);
}